// Round 1
// baseline (1916.449 us; speedup 1.0000x reference)
//
#include <hip/hip_runtime.h>
#include <cstdint>

// Problem constants
// B=2, D=256, L=512, NL=2, DS=16, DC=4
// group a: tokens M=2*256=512, d_model=512, d_inner=1024, r=32, NX=64
// group b: tokens M=2*512=1024, d_model=256, d_inner=512,  r=16, NX=48

// ---------------- GEMM: C(M,N) = A(M,K) @ W(N,K)^T ----------------
__global__ __launch_bounds__(256)
void gemm_tn(const float* __restrict__ A, const float* __restrict__ W,
             float* __restrict__ C, int M, int N, int K)
{
    __shared__ float sA[32][65]; // [k][m], padded
    __shared__ float sW[32][65]; // [k][n], padded
    const int tid = threadIdx.x;
    const int bm = blockIdx.y * 64, bn = blockIdx.x * 64;
    const int tx = tid & 15, ty = tid >> 4;
    float acc[4][4] = {{0.f, 0.f, 0.f, 0.f}};
    const int lr = tid >> 2;        // 0..63
    const int lc = (tid & 3) << 3;  // 0,8,16,24

    for (int k0 = 0; k0 < K; k0 += 32) {
        const int gm = bm + lr;
        const int gn = bn + lr;
#pragma unroll
        for (int i = 0; i < 8; ++i) {
            const int kk = k0 + lc + i;
            float va = (gm < M && kk < K) ? A[(size_t)gm * K + kk] : 0.f;
            float vw = (gn < N && kk < K) ? W[(size_t)gn * K + kk] : 0.f;
            sA[lc + i][lr] = va;
            sW[lc + i][lr] = vw;
        }
        __syncthreads();
#pragma unroll
        for (int kk = 0; kk < 32; ++kk) {
            float a[4], w[4];
#pragma unroll
            for (int i = 0; i < 4; ++i) a[i] = sA[kk][ty * 4 + i];
#pragma unroll
            for (int j = 0; j < 4; ++j) w[j] = sW[kk][tx * 4 + j];
#pragma unroll
            for (int i = 0; i < 4; ++i)
#pragma unroll
                for (int j = 0; j < 4; ++j)
                    acc[i][j] += a[i] * w[j];
        }
        __syncthreads();
    }
#pragma unroll
    for (int i = 0; i < 4; ++i) {
        const int gm = bm + ty * 4 + i;
        if (gm >= M) continue;
#pragma unroll
        for (int j = 0; j < 4; ++j) {
            const int gn = bn + tx * 4 + j;
            if (gn < N) C[(size_t)gm * N + gn] = acc[i][j];
        }
    }
}

// ---------------- causal depthwise conv (DC=4) + SiLU ----------------
// xz: (Bb, Lb, 2*DI); uses first DI channels. out xi: (Bb, Lb, DI)
__global__ __launch_bounds__(256)
void conv_silu(const float* __restrict__ xz, const float* __restrict__ conv_w,
               const float* __restrict__ conv_b, float* __restrict__ xi_out,
               int Bb, int Lb, int DI)
{
    const int idx = blockIdx.x * 256 + threadIdx.x;
    const int total = Bb * Lb * DI;
    if (idx >= total) return;
    const int d = idx % DI;
    const int t = (idx / DI) % Lb;
    const int b = idx / (DI * Lb);
    const float* w = conv_w + (size_t)d * 4;
    float acc = conv_b[d];
    const size_t row2 = (size_t)(b * Lb) * (2 * DI);
#pragma unroll
    for (int j = 0; j < 4; ++j) {
        const int tt = t - 3 + j;
        if (tt >= 0) acc += w[j] * xz[row2 + (size_t)tt * (2 * DI) + d];
    }
    xi_out[idx] = acc / (1.f + __expf(-acc)); // silu
}

// ---------------- fused x_proj + dt_proj(+softplus) ----------------
// one block (256 thr) per token row m. xi: (M,DI). xproj_w: (NX,DI).
// dt_w: (DI,R). outputs x_dbl (M,NX), dt (M,DI)
__global__ __launch_bounds__(256)
void xproj_dt(const float* __restrict__ xi, const float* __restrict__ xproj_w,
              const float* __restrict__ dt_w, const float* __restrict__ dt_b,
              float* __restrict__ x_dbl, float* __restrict__ dt_out,
              int M, int DI, int NX, int R)
{
    __shared__ float s_xi[1024];
    __shared__ float s_dbl[64];
    const int m = blockIdx.x;
    const int tid = threadIdx.x;
    const float* xrow = xi + (size_t)m * DI;
    for (int i = tid; i < DI; i += 256) s_xi[i] = xrow[i];
    __syncthreads();

    // phase 1: x_dbl row (NX <= 64 outputs), 4 lanes per output
    const int n = tid >> 2, g = tid & 3;
    if (n < NX) {
        const float* wrow = xproj_w + (size_t)n * DI;
        float acc = 0.f;
        for (int k = g; k < DI; k += 4) acc += s_xi[k] * wrow[k];
        acc += __shfl_xor(acc, 1);
        acc += __shfl_xor(acc, 2);
        if (g == 0) {
            s_dbl[n] = acc;
            x_dbl[(size_t)m * NX + n] = acc;
        }
    }
    __syncthreads();

    // phase 2: dt row (DI outputs), K = R from LDS
    const int per = DI / 256;
    for (int ii = 0; ii < per; ++ii) {
        const int d = ii * 256 + tid;
        const float* wr = dt_w + (size_t)d * R;
        float a2 = dt_b[d];
        for (int r2 = 0; r2 < R; ++r2) a2 += s_dbl[r2] * wr[r2];
        // softplus = max(x,0) + log1p(exp(-|x|))
        dt_out[(size_t)m * DI + d] = fmaxf(a2, 0.f) + log1pf(expf(-fabsf(a2)));
    }
}

// ---------------- selective scan + D-skip + z-gate ----------------
// block = 256 thr = 16 d x 16 s. grid = Bb * DI/16.
__global__ __launch_bounds__(256)
void scan_gate(const float* __restrict__ dt, const float* __restrict__ xi,
               const float* __restrict__ xdbl, const float* __restrict__ xz,
               const float* __restrict__ A_log, const float* __restrict__ Dp,
               float* __restrict__ y, int Bb, int Lb, int DI, int NX, int R)
{
    const int tid = threadIdx.x;
    const int s = tid & 15, dl = tid >> 4;
    const int nDB = DI / 16;
    const int b = blockIdx.x / nDB;
    const int d = (blockIdx.x % nDB) * 16 + dl;

    const float A = -expf(A_log[(size_t)d * 16 + s]);
    const float Dv = Dp[d];
    float h = 0.f;
    const size_t rowbase = (size_t)b * Lb;
    for (int t = 0; t < Lb; ++t) {
        const size_t m = rowbase + t;
        const float dtv = dt[m * DI + d];
        const float xv = xi[m * DI + d];
        const float Bv = xdbl[m * NX + R + s];
        const float Cv = xdbl[m * NX + R + 16 + s];
        const float dA = expf(dtv * A);
        h = dA * h + dtv * Bv * xv;
        float p = h * Cv;
        p += __shfl_xor(p, 1, 16);
        p += __shfl_xor(p, 2, 16);
        p += __shfl_xor(p, 4, 16);
        p += __shfl_xor(p, 8, 16);
        if (s == 0) {
            const float zv = xz[m * (size_t)(2 * DI) + DI + d];
            y[m * DI + d] = (p + Dv * xv) * (zv / (1.f + expf(-zv)));
        }
    }
}

// ---------------- transpose (Bb, R, C) -> (Bb, C, R) ----------------
__global__ void transpose_k(const float* __restrict__ in, float* __restrict__ out,
                            int Bb, int R, int Cc)
{
    __shared__ float tile[32][33];
    const int b = blockIdx.z;
    const int r0 = blockIdx.y * 32, c0 = blockIdx.x * 32;
    const int tx = threadIdx.x, ty = threadIdx.y; // 32x8
    for (int i = ty; i < 32; i += 8) {
        const int r = r0 + i, c = c0 + tx;
        if (r < R && c < Cc) tile[i][tx] = in[((size_t)b * R + r) * Cc + c];
    }
    __syncthreads();
    for (int i = ty; i < 32; i += 8) {
        const int c = c0 + i, r = r0 + tx;
        if (c < Cc && r < R) out[((size_t)b * Cc + c) * R + r] = tile[tx][i];
    }
}

// ---------------- final: out(b,d,l) = x(b,d,l) + hb(b,l,d) ----------------
// x,out: (2,256,512); hb: (2,512,256)
__global__ __launch_bounds__(256)
void final_add(const float* __restrict__ x, const float* __restrict__ hb,
               float* __restrict__ out)
{
    const int idx = blockIdx.x * 256 + threadIdx.x;
    if (idx >= 2 * 256 * 512) return;
    const int l = idx & 511;
    const int d = (idx >> 9) & 255;
    const int b = idx >> 17;
    out[idx] = x[idx] + hb[(size_t)b * 512 * 256 + (size_t)l * 256 + d];
}

extern "C" void kernel_launch(void* const* d_in, const int* in_sizes, int n_in,
                              void* d_out, int out_size, void* d_ws, size_t ws_size,
                              hipStream_t stream)
{
    const float* x       = (const float*)d_in[0];
    const float* a_in_w  = (const float*)d_in[1];
    const float* a_convw = (const float*)d_in[2];
    const float* a_convb = (const float*)d_in[3];
    const float* a_xproj = (const float*)d_in[4];
    const float* a_dtw   = (const float*)d_in[5];
    const float* a_dtb   = (const float*)d_in[6];
    const float* a_Alog  = (const float*)d_in[7];
    const float* a_Dp    = (const float*)d_in[8];
    const float* a_outw  = (const float*)d_in[9];
    const float* b_in_w  = (const float*)d_in[10];
    const float* b_convw = (const float*)d_in[11];
    const float* b_convb = (const float*)d_in[12];
    const float* b_xproj = (const float*)d_in[13];
    const float* b_dtw   = (const float*)d_in[14];
    const float* b_dtb   = (const float*)d_in[15];
    const float* b_Alog  = (const float*)d_in[16];
    const float* b_Dp    = (const float*)d_in[17];
    const float* b_outw  = (const float*)d_in[18];

    float* ws = (float*)d_ws;
    float* buf_x   = ws;                 // 262144
    float* buf_xz  = buf_x  + 262144;    // 1048576
    float* buf_xi  = buf_xz + 1048576;   // 524288
    float* buf_dbl = buf_xi + 524288;    // 65536
    float* buf_dt  = buf_dbl + 65536;    // 524288
    float* buf_y   = buf_dt + 524288;    // 524288
    float* buf_x2  = buf_y  + 524288;    // 262144

    // -------- group a: b=2, l=256, dm=512, di=1024, r=32, NX=64 --------
    for (int k = 0; k < 2; ++k) {
        const int Bb = 2, Lb = 256, DM = 512, DI = 1024, R = 32, NX = 64;
        const int M = Bb * Lb;
        const float* src = (k == 0) ? x : buf_x;
        gemm_tn<<<dim3(2 * DI / 64, M / 64), 256, 0, stream>>>(
            src, a_in_w + (size_t)k * 2 * DI * DM, buf_xz, M, 2 * DI, DM);
        conv_silu<<<(M * DI + 255) / 256, 256, 0, stream>>>(
            buf_xz, a_convw + (size_t)k * DI * 4, a_convb + (size_t)k * DI,
            buf_xi, Bb, Lb, DI);
        xproj_dt<<<M, 256, 0, stream>>>(
            buf_xi, a_xproj + (size_t)k * NX * DI, a_dtw + (size_t)k * DI * R,
            a_dtb + (size_t)k * DI, buf_dbl, buf_dt, M, DI, NX, R);
        scan_gate<<<Bb * DI / 16, 256, 0, stream>>>(
            buf_dt, buf_xi, buf_dbl, buf_xz, a_Alog + (size_t)k * DI * 16,
            a_Dp + (size_t)k * DI, buf_y, Bb, Lb, DI, NX, R);
        gemm_tn<<<dim3(DM / 64, M / 64), 256, 0, stream>>>(
            buf_y, a_outw + (size_t)k * DM * DI, buf_x, M, DM, DI);
    }

    // transpose (2,256,512) -> (2,512,256)
    transpose_k<<<dim3(512 / 32, 256 / 32, 2), dim3(32, 8), 0, stream>>>(
        buf_x, buf_x2, 2, 256, 512);

    // -------- group b: b=2, l=512, dm=256, di=512, r=16, NX=48 --------
    for (int k = 0; k < 2; ++k) {
        const int Bb = 2, Lb = 512, DM = 256, DI = 512, R = 16, NX = 48;
        const int M = Bb * Lb;
        const float* src = (k == 0) ? buf_x2 : buf_x;
        gemm_tn<<<dim3(2 * DI / 64, M / 64), 256, 0, stream>>>(
            src, b_in_w + (size_t)k * 2 * DI * DM, buf_xz, M, 2 * DI, DM);
        conv_silu<<<(M * DI + 255) / 256, 256, 0, stream>>>(
            buf_xz, b_convw + (size_t)k * DI * 4, b_convb + (size_t)k * DI,
            buf_xi, Bb, Lb, DI);
        xproj_dt<<<M, 256, 0, stream>>>(
            buf_xi, b_xproj + (size_t)k * NX * DI, b_dtw + (size_t)k * DI * R,
            b_dtb + (size_t)k * DI, buf_dbl, buf_dt, M, DI, NX, R);
        scan_gate<<<Bb * DI / 16, 256, 0, stream>>>(
            buf_dt, buf_xi, buf_dbl, buf_xz, b_Alog + (size_t)k * DI * 16,
            b_Dp + (size_t)k * DI, buf_y, Bb, Lb, DI, NX, R);
        gemm_tn<<<dim3(DM / 64, M / 64), 256, 0, stream>>>(
            buf_y, b_outw + (size_t)k * DM * DI, buf_x, M, DM, DI);
    }

    // out = x + transpose(buf_x)
    final_add<<<(2 * 256 * 512 + 255) / 256, 256, 0, stream>>>(
        x, buf_x, (float*)d_out);
}

// Round 2
// 1069.264 us; speedup vs baseline: 1.7923x; 1.7923x over previous
//
#include <hip/hip_runtime.h>
#include <cstdint>

// Problem constants
// B=2, D=256, L=512, NL=2, DS=16, DC=4
// group a: tokens M=2*256=512, d_model=512, d_inner=1024, r=32, NX=64
// group b: tokens M=2*512=1024, d_model=256, d_inner=512,  r=16, NX=48

// ---------------- GEMM: C(M,N) = A(M,K) @ W(N,K)^T ----------------
__global__ __launch_bounds__(256)
void gemm_tn(const float* __restrict__ A, const float* __restrict__ W,
             float* __restrict__ C, int M, int N, int K)
{
    __shared__ float sA[32][65]; // [k][m], padded
    __shared__ float sW[32][65]; // [k][n], padded
    const int tid = threadIdx.x;
    const int bm = blockIdx.y * 64, bn = blockIdx.x * 64;
    const int tx = tid & 15, ty = tid >> 4;
    float acc[4][4] = {{0.f, 0.f, 0.f, 0.f}};
    const int lr = tid >> 2;        // 0..63
    const int lc = (tid & 3) << 3;  // 0,8,16,24

    for (int k0 = 0; k0 < K; k0 += 32) {
        const int gm = bm + lr;
        const int gn = bn + lr;
#pragma unroll
        for (int i = 0; i < 8; ++i) {
            const int kk = k0 + lc + i;
            float va = (gm < M && kk < K) ? A[(size_t)gm * K + kk] : 0.f;
            float vw = (gn < N && kk < K) ? W[(size_t)gn * K + kk] : 0.f;
            sA[lc + i][lr] = va;
            sW[lc + i][lr] = vw;
        }
        __syncthreads();
#pragma unroll
        for (int kk = 0; kk < 32; ++kk) {
            float a[4], w[4];
#pragma unroll
            for (int i = 0; i < 4; ++i) a[i] = sA[kk][ty * 4 + i];
#pragma unroll
            for (int j = 0; j < 4; ++j) w[j] = sW[kk][tx * 4 + j];
#pragma unroll
            for (int i = 0; i < 4; ++i)
#pragma unroll
                for (int j = 0; j < 4; ++j)
                    acc[i][j] += a[i] * w[j];
        }
        __syncthreads();
    }
#pragma unroll
    for (int i = 0; i < 4; ++i) {
        const int gm = bm + ty * 4 + i;
        if (gm >= M) continue;
#pragma unroll
        for (int j = 0; j < 4; ++j) {
            const int gn = bn + tx * 4 + j;
            if (gn < N) C[(size_t)gm * N + gn] = acc[i][j];
        }
    }
}

// ---------------- causal depthwise conv (DC=4) + SiLU ----------------
__global__ __launch_bounds__(256)
void conv_silu(const float* __restrict__ xz, const float* __restrict__ conv_w,
               const float* __restrict__ conv_b, float* __restrict__ xi_out,
               int Bb, int Lb, int DI)
{
    const int idx = blockIdx.x * 256 + threadIdx.x;
    const int total = Bb * Lb * DI;
    if (idx >= total) return;
    const int d = idx % DI;
    const int t = (idx / DI) % Lb;
    const int b = idx / (DI * Lb);
    const float* w = conv_w + (size_t)d * 4;
    float acc = conv_b[d];
    const size_t row2 = (size_t)(b * Lb) * (2 * DI);
#pragma unroll
    for (int j = 0; j < 4; ++j) {
        const int tt = t - 3 + j;
        if (tt >= 0) acc += w[j] * xz[row2 + (size_t)tt * (2 * DI) + d];
    }
    xi_out[idx] = acc / (1.f + __expf(-acc)); // silu
}

// ---------------- fused x_proj + dt_proj(+softplus) ----------------
__global__ __launch_bounds__(256)
void xproj_dt(const float* __restrict__ xi, const float* __restrict__ xproj_w,
              const float* __restrict__ dt_w, const float* __restrict__ dt_b,
              float* __restrict__ x_dbl, float* __restrict__ dt_out,
              int M, int DI, int NX, int R)
{
    __shared__ float s_xi[1024];
    __shared__ float s_dbl[64];
    const int m = blockIdx.x;
    const int tid = threadIdx.x;
    const float* xrow = xi + (size_t)m * DI;
    for (int i = tid; i < DI; i += 256) s_xi[i] = xrow[i];
    __syncthreads();

    const int n = tid >> 2, g = tid & 3;
    if (n < NX) {
        const float* wrow = xproj_w + (size_t)n * DI;
        float acc = 0.f;
        for (int k = g; k < DI; k += 4) acc += s_xi[k] * wrow[k];
        acc += __shfl_xor(acc, 1);
        acc += __shfl_xor(acc, 2);
        if (g == 0) {
            s_dbl[n] = acc;
            x_dbl[(size_t)m * NX + n] = acc;
        }
    }
    __syncthreads();

    const int per = DI / 256;
    for (int ii = 0; ii < per; ++ii) {
        const int d = ii * 256 + tid;
        const float* wr = dt_w + (size_t)d * R;
        float a2 = dt_b[d];
        for (int r2 = 0; r2 < R; ++r2) a2 += s_dbl[r2] * wr[r2];
        dt_out[(size_t)m * DI + d] = fmaxf(a2, 0.f) + log1pf(__expf(-fabsf(a2)));
    }
}

// ---------------- selective scan + D-skip + z-gate (LDS chunked) ----------------
// block = 256 thr = 16 d x 16 s. grid = Bb * DI/16. T_CHUNK timesteps staged at a time.
#define T_CHUNK 32
__global__ __launch_bounds__(256)
void scan_gate2(const float* __restrict__ dt, const float* __restrict__ xi,
                const float* __restrict__ xdbl, const float* __restrict__ xz,
                const float* __restrict__ A_log, const float* __restrict__ Dp,
                float* __restrict__ y, int Bb, int Lb, int DI, int NX, int R)
{
    __shared__ float s_dt[2][T_CHUNK][16];
    __shared__ float s_xi[2][T_CHUNK][16];
    __shared__ float s_z [2][T_CHUNK][16];
    __shared__ float s_bc[2][T_CHUNK][32];
    __shared__ float s_y [2][T_CHUNK][16];
    const int tid = threadIdx.x;
    const int s = tid & 15, dl = tid >> 4;
    const int nDB = DI / 16;
    const int b = blockIdx.x / nDB;
    const int d0 = (blockIdx.x % nDB) * 16;
    const int d = d0 + dl;
    const float A = -__expf(A_log[(size_t)d * 16 + s]);
    const float Dv = Dp[d];
    const size_t rowbase = (size_t)b * Lb;
    const int NC = Lb / T_CHUNK;

    auto stage = [&](int buf, int c) {
        const int t0 = c * T_CHUNK;
#pragma unroll
        for (int i = 0; i < 2; ++i) {
            const int e = i * 256 + tid;
            const int tt = e >> 4, dd = e & 15;
            const size_t m = rowbase + t0 + tt;
            s_dt[buf][tt][dd] = dt[m * DI + d0 + dd];
            s_xi[buf][tt][dd] = xi[m * DI + d0 + dd];
            s_z [buf][tt][dd] = xz[m * (size_t)(2 * DI) + DI + d0 + dd];
        }
#pragma unroll
        for (int i = 0; i < 4; ++i) {
            const int e = i * 256 + tid;
            const int tt = e >> 5, j = e & 31;
            const size_t m = rowbase + t0 + tt;
            s_bc[buf][tt][j] = xdbl[m * NX + R + j];
        }
    };

    stage(0, 0);
    __syncthreads();
    float h = 0.f;
    for (int c = 0; c < NC; ++c) {
        const int buf = c & 1;
        if (c + 1 < NC) stage(buf ^ 1, c + 1);
#pragma unroll 8
        for (int t = 0; t < T_CHUNK; ++t) {
            const float dtv = s_dt[buf][t][dl];
            const float xv  = s_xi[buf][t][dl];
            const float Bv  = s_bc[buf][t][s];
            const float Cv  = s_bc[buf][t][16 + s];
            const float dA = __expf(dtv * A);
            h = fmaf(dA, h, dtv * Bv * xv);
            float p = h * Cv;
            p += __shfl_xor(p, 1, 16);
            p += __shfl_xor(p, 2, 16);
            p += __shfl_xor(p, 4, 16);
            p += __shfl_xor(p, 8, 16);
            if (s == 0) {
                const float zv = s_z[buf][t][dl];
                const float sig = __fdividef(zv, 1.f + __expf(-zv));
                s_y[buf][t][dl] = (p + Dv * xv) * sig;
            }
        }
        __syncthreads();
        const int t0 = c * T_CHUNK;
#pragma unroll
        for (int i = 0; i < 2; ++i) {
            const int e = i * 256 + tid;
            const int tt = e >> 4, dd = e & 15;
            y[(rowbase + t0 + tt) * DI + d0 + dd] = s_y[buf][tt][dd];
        }
    }
}

// ---------------- transpose (Bb, R, C) -> (Bb, C, R) ----------------
__global__ void transpose_k(const float* __restrict__ in, float* __restrict__ out,
                            int Bb, int R, int Cc)
{
    __shared__ float tile[32][33];
    const int b = blockIdx.z;
    const int r0 = blockIdx.y * 32, c0 = blockIdx.x * 32;
    const int tx = threadIdx.x, ty = threadIdx.y; // 32x8
    for (int i = ty; i < 32; i += 8) {
        const int r = r0 + i, c = c0 + tx;
        if (r < R && c < Cc) tile[i][tx] = in[((size_t)b * R + r) * Cc + c];
    }
    __syncthreads();
    for (int i = ty; i < 32; i += 8) {
        const int c = c0 + i, r = r0 + tx;
        if (c < Cc && r < R) out[((size_t)b * Cc + c) * R + r] = tile[tx][i];
    }
}

// ---------------- final: out(b,d,l) = x(b,d,l) + hb(b,l,d) ----------------
__global__ __launch_bounds__(256)
void final_add(const float* __restrict__ x, const float* __restrict__ hb,
               float* __restrict__ out)
{
    const int idx = blockIdx.x * 256 + threadIdx.x;
    if (idx >= 2 * 256 * 512) return;
    const int l = idx & 511;
    const int d = (idx >> 9) & 255;
    const int b = idx >> 17;
    out[idx] = x[idx] + hb[(size_t)b * 512 * 256 + (size_t)l * 256 + d];
}

extern "C" void kernel_launch(void* const* d_in, const int* in_sizes, int n_in,
                              void* d_out, int out_size, void* d_ws, size_t ws_size,
                              hipStream_t stream)
{
    const float* x       = (const float*)d_in[0];
    const float* a_in_w  = (const float*)d_in[1];
    const float* a_convw = (const float*)d_in[2];
    const float* a_convb = (const float*)d_in[3];
    const float* a_xproj = (const float*)d_in[4];
    const float* a_dtw   = (const float*)d_in[5];
    const float* a_dtb   = (const float*)d_in[6];
    const float* a_Alog  = (const float*)d_in[7];
    const float* a_Dp    = (const float*)d_in[8];
    const float* a_outw  = (const float*)d_in[9];
    const float* b_in_w  = (const float*)d_in[10];
    const float* b_convw = (const float*)d_in[11];
    const float* b_convb = (const float*)d_in[12];
    const float* b_xproj = (const float*)d_in[13];
    const float* b_dtw   = (const float*)d_in[14];
    const float* b_dtb   = (const float*)d_in[15];
    const float* b_Alog  = (const float*)d_in[16];
    const float* b_Dp    = (const float*)d_in[17];
    const float* b_outw  = (const float*)d_in[18];

    float* ws = (float*)d_ws;
    float* buf_x   = ws;                 // 262144
    float* buf_xz  = buf_x  + 262144;    // 1048576
    float* buf_xi  = buf_xz + 1048576;   // 524288
    float* buf_dbl = buf_xi + 524288;    // 65536
    float* buf_dt  = buf_dbl + 65536;    // 524288
    float* buf_y   = buf_dt + 524288;    // 524288
    float* buf_x2  = buf_y  + 524288;    // 262144

    // -------- group a: b=2, l=256, dm=512, di=1024, r=32, NX=64 --------
    for (int k = 0; k < 2; ++k) {
        const int Bb = 2, Lb = 256, DM = 512, DI = 1024, R = 32, NX = 64;
        const int M = Bb * Lb;
        const float* src = (k == 0) ? x : buf_x;
        gemm_tn<<<dim3(2 * DI / 64, M / 64), 256, 0, stream>>>(
            src, a_in_w + (size_t)k * 2 * DI * DM, buf_xz, M, 2 * DI, DM);
        conv_silu<<<(M * DI + 255) / 256, 256, 0, stream>>>(
            buf_xz, a_convw + (size_t)k * DI * 4, a_convb + (size_t)k * DI,
            buf_xi, Bb, Lb, DI);
        xproj_dt<<<M, 256, 0, stream>>>(
            buf_xi, a_xproj + (size_t)k * NX * DI, a_dtw + (size_t)k * DI * R,
            a_dtb + (size_t)k * DI, buf_dbl, buf_dt, M, DI, NX, R);
        scan_gate2<<<Bb * DI / 16, 256, 0, stream>>>(
            buf_dt, buf_xi, buf_dbl, buf_xz, a_Alog + (size_t)k * DI * 16,
            a_Dp + (size_t)k * DI, buf_y, Bb, Lb, DI, NX, R);
        gemm_tn<<<dim3(DM / 64, M / 64), 256, 0, stream>>>(
            buf_y, a_outw + (size_t)k * DM * DI, buf_x, M, DM, DI);
    }

    // transpose (2,256,512) -> (2,512,256)
    transpose_k<<<dim3(512 / 32, 256 / 32, 2), dim3(32, 8), 0, stream>>>(
        buf_x, buf_x2, 2, 256, 512);

    // -------- group b: b=2, l=512, dm=256, di=512, r=16, NX=48 --------
    for (int k = 0; k < 2; ++k) {
        const int Bb = 2, Lb = 512, DM = 256, DI = 512, R = 16, NX = 48;
        const int M = Bb * Lb;
        const float* src = (k == 0) ? buf_x2 : buf_x;
        gemm_tn<<<dim3(2 * DI / 64, M / 64), 256, 0, stream>>>(
            src, b_in_w + (size_t)k * 2 * DI * DM, buf_xz, M, 2 * DI, DM);
        conv_silu<<<(M * DI + 255) / 256, 256, 0, stream>>>(
            buf_xz, b_convw + (size_t)k * DI * 4, b_convb + (size_t)k * DI,
            buf_xi, Bb, Lb, DI);
        xproj_dt<<<M, 256, 0, stream>>>(
            buf_xi, b_xproj + (size_t)k * NX * DI, b_dtw + (size_t)k * DI * R,
            b_dtb + (size_t)k * DI, buf_dbl, buf_dt, M, DI, NX, R);
        scan_gate2<<<Bb * DI / 16, 256, 0, stream>>>(
            buf_dt, buf_xi, buf_dbl, buf_xz, b_Alog + (size_t)k * DI * 16,
            b_Dp + (size_t)k * DI, buf_y, Bb, Lb, DI, NX, R);
        gemm_tn<<<dim3(DM / 64, M / 64), 256, 0, stream>>>(
            buf_y, b_outw + (size_t)k * DM * DI, buf_x, M, DM, DI);
    }

    // out = x + transpose(buf_x)
    final_add<<<(2 * 256 * 512 + 255) / 256, 256, 0, stream>>>(
        x, buf_x, (float*)d_out);
}

// Round 3
// 501.719 us; speedup vs baseline: 3.8198x; 2.1312x over previous
//
#include <hip/hip_runtime.h>
#include <cstdint>

typedef float float4v __attribute__((ext_vector_type(4)));

// Problem constants
// B=2, D=256, L=512, NL=2, DS=16, DC=4
// group a: tokens M=2*256=512, d_model=512, d_inner=1024, r=32, NX=64, P=8
// group b: tokens M=2*512=1024, d_model=256, d_inner=512,  r=16, NX=48, P=16

// ---------------- GEMM: C(M,N) = A(M,K) @ W(N,K)^T ----------------
// All callers have M,N multiples of 64 and K multiple of 32 -> no guards.
__global__ __launch_bounds__(256)
void gemm_tn(const float* __restrict__ A, const float* __restrict__ W,
             float* __restrict__ C, int M, int N, int K)
{
    __shared__ float sA[32][68]; // [k][m], padded so rows are 16B-aligned
    __shared__ float sW[32][68]; // [k][n]
    const int tid = threadIdx.x;
    const int bm = blockIdx.y * 64, bn = blockIdx.x * 64;
    const int tx = tid & 15, ty = tid >> 4;
    float acc[4][4] = {{0.f, 0.f, 0.f, 0.f}};
    const int lr = tid >> 2;        // 0..63
    const int lc = (tid & 3) << 3;  // 0,8,16,24

    for (int k0 = 0; k0 < K; k0 += 32) {
        const float4v va0 = *(const float4v*)&A[(size_t)(bm + lr) * K + k0 + lc];
        const float4v va1 = *(const float4v*)&A[(size_t)(bm + lr) * K + k0 + lc + 4];
        const float4v vw0 = *(const float4v*)&W[(size_t)(bn + lr) * K + k0 + lc];
        const float4v vw1 = *(const float4v*)&W[(size_t)(bn + lr) * K + k0 + lc + 4];
#pragma unroll
        for (int i = 0; i < 4; ++i) {
            sA[lc + i][lr] = va0[i];
            sA[lc + 4 + i][lr] = va1[i];
            sW[lc + i][lr] = vw0[i];
            sW[lc + 4 + i][lr] = vw1[i];
        }
        __syncthreads();
#pragma unroll
        for (int kk = 0; kk < 32; ++kk) {
            const float4v a4 = *(const float4v*)&sA[kk][ty * 4];
            const float4v w4 = *(const float4v*)&sW[kk][tx * 4];
#pragma unroll
            for (int i = 0; i < 4; ++i)
#pragma unroll
                for (int j = 0; j < 4; ++j)
                    acc[i][j] += a4[i] * w4[j];
        }
        __syncthreads();
    }
#pragma unroll
    for (int i = 0; i < 4; ++i) {
        const int gm = bm + ty * 4 + i;
#pragma unroll
        for (int j = 0; j < 4; ++j)
            C[(size_t)gm * N + bn + tx * 4 + j] = acc[i][j];
    }
}

// ---------------- causal depthwise conv (DC=4) + SiLU ----------------
__global__ __launch_bounds__(256)
void conv_silu(const float* __restrict__ xz, const float* __restrict__ conv_w,
               const float* __restrict__ conv_b, float* __restrict__ xi_out,
               int Bb, int Lb, int DI)
{
    const int idx = blockIdx.x * 256 + threadIdx.x;
    const int total = Bb * Lb * DI;
    if (idx >= total) return;
    const int d = idx % DI;
    const int t = (idx / DI) % Lb;
    const int b = idx / (DI * Lb);
    const float* w = conv_w + (size_t)d * 4;
    float acc = conv_b[d];
    const size_t row2 = (size_t)(b * Lb) * (2 * DI);
#pragma unroll
    for (int j = 0; j < 4; ++j) {
        const int tt = t - 3 + j;
        if (tt >= 0) acc += w[j] * xz[row2 + (size_t)tt * (2 * DI) + d];
    }
    xi_out[idx] = acc / (1.f + __expf(-acc)); // silu
}

// ---------------- fused x_proj + dt_proj(+softplus) ----------------
__global__ __launch_bounds__(256)
void xproj_dt(const float* __restrict__ xi, const float* __restrict__ xproj_w,
              const float* __restrict__ dt_w, const float* __restrict__ dt_b,
              float* __restrict__ x_dbl, float* __restrict__ dt_out,
              int M, int DI, int NX, int R)
{
    __shared__ float s_xi[1024];
    __shared__ float s_dbl[64];
    const int m = blockIdx.x;
    const int tid = threadIdx.x;
    const float* xrow = xi + (size_t)m * DI;
    for (int i = tid; i < DI; i += 256) s_xi[i] = xrow[i];
    __syncthreads();

    const int n = tid >> 2, g = tid & 3;
    if (n < NX) {
        const float* wrow = xproj_w + (size_t)n * DI;
        float acc = 0.f;
        for (int k = g; k < DI; k += 4) acc += s_xi[k] * wrow[k];
        acc += __shfl_xor(acc, 1);
        acc += __shfl_xor(acc, 2);
        if (g == 0) {
            s_dbl[n] = acc;
            x_dbl[(size_t)m * NX + n] = acc;
        }
    }
    __syncthreads();

    const int per = DI / 256;
    for (int ii = 0; ii < per; ++ii) {
        const int d = ii * 256 + tid;
        const float* wr = dt_w + (size_t)d * R;
        float a2 = dt_b[d];
        for (int r2 = 0; r2 < R; ++r2) a2 += s_dbl[r2] * wr[r2];
        dt_out[(size_t)m * DI + d] = fmaxf(a2, 0.f) + log1pf(__expf(-fabsf(a2)));
    }
}

// ---------------- chunked parallel selective scan ----------------
// chunk size = 32 timesteps. phase1: per-chunk propagator + local end state.
// phase2: serial combine over chunks. phase3: re-scan chunk from known h_init,
// emit y with D-skip and z-gate.
// block = 256 thr = 16 d x 16 s. grid = Bb * P * DI/16.

__global__ __launch_bounds__(256)
void scan_p1(const float* __restrict__ dt, const float* __restrict__ xi,
             const float* __restrict__ xdbl, const float* __restrict__ A_log,
             float* __restrict__ wsA, float* __restrict__ wsB,
             int Bb, int Lb, int DI, int NX, int R, int P)
{
    const int tid = threadIdx.x;
    const int s = tid & 15, dl = tid >> 4;
    const int nDB = DI / 16;
    const int cpb = P * nDB;
    const int b = blockIdx.x / cpb;
    const int rem = blockIdx.x % cpb;
    const int c = rem / nDB;
    const int d = (rem % nDB) * 16 + dl;
    const int TC = Lb / P;
    const float A = -__expf(A_log[(size_t)d * 16 + s]);
    float h = 0.f, sdt = 0.f;
    const size_t rowbase = (size_t)b * Lb + (size_t)c * TC;
#pragma unroll 4
    for (int t = 0; t < TC; ++t) {
        const size_t m = rowbase + t;
        const float dtv = dt[m * DI + d];
        const float xv  = xi[m * DI + d];
        const float Bv  = xdbl[m * NX + R + s];
        const float dA = __expf(dtv * A);
        h = fmaf(dA, h, dtv * Bv * xv);
        sdt += dtv;
    }
    const size_t o = ((size_t)(b * P + c) * DI + d) * 16 + s;
    wsA[o] = __expf(sdt * A);  // prod of dA over the chunk
    wsB[o] = h;
}

__global__ __launch_bounds__(256)
void scan_p2(const float* __restrict__ wsA, const float* __restrict__ wsB,
             float* __restrict__ wsH, int Bb, int DI, int P)
{
    const int idx = blockIdx.x * 256 + threadIdx.x;
    const int per_b = DI * 16;
    if (idx >= Bb * per_b) return;
    const int b = idx / per_b, ds_ = idx % per_b;
    float h = 0.f;
    for (int c = 0; c < P; ++c) {
        const size_t o = (size_t)(b * P + c) * per_b + ds_;
        wsH[o] = h;
        h = fmaf(wsA[o], h, wsB[o]);
    }
}

__global__ __launch_bounds__(256)
void scan_p3(const float* __restrict__ dt, const float* __restrict__ xi,
             const float* __restrict__ xdbl, const float* __restrict__ xz,
             const float* __restrict__ A_log, const float* __restrict__ Dp,
             const float* __restrict__ wsH, float* __restrict__ y,
             int Bb, int Lb, int DI, int NX, int R, int P)
{
    const int tid = threadIdx.x;
    const int s = tid & 15, dl = tid >> 4;
    const int nDB = DI / 16;
    const int cpb = P * nDB;
    const int b = blockIdx.x / cpb;
    const int rem = blockIdx.x % cpb;
    const int c = rem / nDB;
    const int d = (rem % nDB) * 16 + dl;
    const int TC = Lb / P;
    const float A = -__expf(A_log[(size_t)d * 16 + s]);
    const float Dv = Dp[d];
    const size_t o = ((size_t)(b * P + c) * DI + d) * 16 + s;
    float h = wsH[o];
    const size_t rowbase = (size_t)b * Lb + (size_t)c * TC;
#pragma unroll 2
    for (int t = 0; t < TC; ++t) {
        const size_t m = rowbase + t;
        const float dtv = dt[m * DI + d];
        const float xv  = xi[m * DI + d];
        const float Bv  = xdbl[m * NX + R + s];
        const float Cv  = xdbl[m * NX + R + 16 + s];
        const float zv  = xz[m * (size_t)(2 * DI) + DI + d];
        const float dA = __expf(dtv * A);
        h = fmaf(dA, h, dtv * Bv * xv);
        float p = h * Cv;
        p += __shfl_xor(p, 1, 16);
        p += __shfl_xor(p, 2, 16);
        p += __shfl_xor(p, 4, 16);
        p += __shfl_xor(p, 8, 16);
        if (s == 0) {
            const float sig = __fdividef(zv, 1.f + __expf(-zv));
            y[m * DI + d] = (p + Dv * xv) * sig;
        }
    }
}

// ---------------- transpose (Bb, R, C) -> (Bb, C, R) ----------------
__global__ void transpose_k(const float* __restrict__ in, float* __restrict__ out,
                            int Bb, int R, int Cc)
{
    __shared__ float tile[32][33];
    const int b = blockIdx.z;
    const int r0 = blockIdx.y * 32, c0 = blockIdx.x * 32;
    const int tx = threadIdx.x, ty = threadIdx.y; // 32x8
    for (int i = ty; i < 32; i += 8) {
        const int r = r0 + i, c = c0 + tx;
        if (r < R && c < Cc) tile[i][tx] = in[((size_t)b * R + r) * Cc + c];
    }
    __syncthreads();
    for (int i = ty; i < 32; i += 8) {
        const int c = c0 + i, r = r0 + tx;
        if (c < Cc && r < R) out[((size_t)b * Cc + c) * R + r] = tile[tx][i];
    }
}

// ---------------- final: out(b,d,l) = x(b,d,l) + hb(b,l,d) ----------------
__global__ __launch_bounds__(256)
void final_add(const float* __restrict__ x, const float* __restrict__ hb,
               float* __restrict__ out)
{
    const int idx = blockIdx.x * 256 + threadIdx.x;
    if (idx >= 2 * 256 * 512) return;
    const int l = idx & 511;
    const int d = (idx >> 9) & 255;
    const int b = idx >> 17;
    out[idx] = x[idx] + hb[(size_t)b * 512 * 256 + (size_t)l * 256 + d];
}

extern "C" void kernel_launch(void* const* d_in, const int* in_sizes, int n_in,
                              void* d_out, int out_size, void* d_ws, size_t ws_size,
                              hipStream_t stream)
{
    const float* x       = (const float*)d_in[0];
    const float* a_in_w  = (const float*)d_in[1];
    const float* a_convw = (const float*)d_in[2];
    const float* a_convb = (const float*)d_in[3];
    const float* a_xproj = (const float*)d_in[4];
    const float* a_dtw   = (const float*)d_in[5];
    const float* a_dtb   = (const float*)d_in[6];
    const float* a_Alog  = (const float*)d_in[7];
    const float* a_Dp    = (const float*)d_in[8];
    const float* a_outw  = (const float*)d_in[9];
    const float* b_in_w  = (const float*)d_in[10];
    const float* b_convw = (const float*)d_in[11];
    const float* b_convb = (const float*)d_in[12];
    const float* b_xproj = (const float*)d_in[13];
    const float* b_dtw   = (const float*)d_in[14];
    const float* b_dtb   = (const float*)d_in[15];
    const float* b_Alog  = (const float*)d_in[16];
    const float* b_Dp    = (const float*)d_in[17];
    const float* b_outw  = (const float*)d_in[18];

    float* ws = (float*)d_ws;
    float* buf_x   = ws;                 // 262144
    float* buf_xz  = buf_x  + 262144;    // 1048576
    float* buf_xi  = buf_xz + 1048576;   // 524288
    float* buf_dbl = buf_xi + 524288;    // 65536
    float* buf_dt  = buf_dbl + 65536;    // 524288
    float* buf_y   = buf_dt + 524288;    // 524288
    float* buf_x2  = buf_y  + 524288;    // 262144
    float* buf_wsA = buf_x2 + 262144;    // 262144
    float* buf_wsB = buf_wsA + 262144;   // 262144
    float* buf_wsH = buf_wsB + 262144;   // 262144

    // -------- group a: b=2, l=256, dm=512, di=1024, r=32, NX=64, P=8 --------
    for (int k = 0; k < 2; ++k) {
        const int Bb = 2, Lb = 256, DM = 512, DI = 1024, R = 32, NX = 64, P = 8;
        const int M = Bb * Lb;
        const float* src = (k == 0) ? x : buf_x;
        gemm_tn<<<dim3(2 * DI / 64, M / 64), 256, 0, stream>>>(
            src, a_in_w + (size_t)k * 2 * DI * DM, buf_xz, M, 2 * DI, DM);
        conv_silu<<<(M * DI + 255) / 256, 256, 0, stream>>>(
            buf_xz, a_convw + (size_t)k * DI * 4, a_convb + (size_t)k * DI,
            buf_xi, Bb, Lb, DI);
        xproj_dt<<<M, 256, 0, stream>>>(
            buf_xi, a_xproj + (size_t)k * NX * DI, a_dtw + (size_t)k * DI * R,
            a_dtb + (size_t)k * DI, buf_dbl, buf_dt, M, DI, NX, R);
        scan_p1<<<Bb * P * DI / 16, 256, 0, stream>>>(
            buf_dt, buf_xi, buf_dbl, a_Alog + (size_t)k * DI * 16,
            buf_wsA, buf_wsB, Bb, Lb, DI, NX, R, P);
        scan_p2<<<(Bb * DI * 16 + 255) / 256, 256, 0, stream>>>(
            buf_wsA, buf_wsB, buf_wsH, Bb, DI, P);
        scan_p3<<<Bb * P * DI / 16, 256, 0, stream>>>(
            buf_dt, buf_xi, buf_dbl, buf_xz, a_Alog + (size_t)k * DI * 16,
            a_Dp + (size_t)k * DI, buf_wsH, buf_y, Bb, Lb, DI, NX, R, P);
        gemm_tn<<<dim3(DM / 64, M / 64), 256, 0, stream>>>(
            buf_y, a_outw + (size_t)k * DM * DI, buf_x, M, DM, DI);
    }

    // transpose (2,256,512) -> (2,512,256)
    transpose_k<<<dim3(512 / 32, 256 / 32, 2), dim3(32, 8), 0, stream>>>(
        buf_x, buf_x2, 2, 256, 512);

    // -------- group b: b=2, l=512, dm=256, di=512, r=16, NX=48, P=16 --------
    for (int k = 0; k < 2; ++k) {
        const int Bb = 2, Lb = 512, DM = 256, DI = 512, R = 16, NX = 48, P = 16;
        const int M = Bb * Lb;
        const float* src = (k == 0) ? buf_x2 : buf_x;
        gemm_tn<<<dim3(2 * DI / 64, M / 64), 256, 0, stream>>>(
            src, b_in_w + (size_t)k * 2 * DI * DM, buf_xz, M, 2 * DI, DM);
        conv_silu<<<(M * DI + 255) / 256, 256, 0, stream>>>(
            buf_xz, b_convw + (size_t)k * DI * 4, b_convb + (size_t)k * DI,
            buf_xi, Bb, Lb, DI);
        xproj_dt<<<M, 256, 0, stream>>>(
            buf_xi, b_xproj + (size_t)k * NX * DI, b_dtw + (size_t)k * DI * R,
            b_dtb + (size_t)k * DI, buf_dbl, buf_dt, M, DI, NX, R);
        scan_p1<<<Bb * P * DI / 16, 256, 0, stream>>>(
            buf_dt, buf_xi, buf_dbl, b_Alog + (size_t)k * DI * 16,
            buf_wsA, buf_wsB, Bb, Lb, DI, NX, R, P);
        scan_p2<<<(Bb * DI * 16 + 255) / 256, 256, 0, stream>>>(
            buf_wsA, buf_wsB, buf_wsH, Bb, DI, P);
        scan_p3<<<Bb * P * DI / 16, 256, 0, stream>>>(
            buf_dt, buf_xi, buf_dbl, buf_xz, b_Alog + (size_t)k * DI * 16,
            b_Dp + (size_t)k * DI, buf_wsH, buf_y, Bb, Lb, DI, NX, R, P);
        gemm_tn<<<dim3(DM / 64, M / 64), 256, 0, stream>>>(
            buf_y, b_outw + (size_t)k * DM * DI, buf_x, M, DM, DI);
    }

    // out = x + transpose(buf_x)
    final_add<<<(2 * 256 * 512 + 255) / 256, 256, 0, stream>>>(
        x, buf_x, (float*)d_out);
}

// Round 4
// 409.904 us; speedup vs baseline: 4.6754x; 1.2240x over previous
//
#include <hip/hip_runtime.h>
#include <cstdint>

typedef float f32x4 __attribute__((ext_vector_type(4)));
typedef __bf16 bf16x8 __attribute__((ext_vector_type(8)));
typedef __bf16 bf16x4 __attribute__((ext_vector_type(4)));

// Problem constants
// B=2, D=256, L=512, NL=2, DS=16, DC=4
// group a: tokens M=2*256=512, d_model=512, d_inner=1024, r=32, NX=64, P=8
// group b: tokens M=2*512=1024, d_model=256, d_inner=512,  r=16, NX=48, P=16

// ---------------- weight f32 -> bf16 conversion (4 segments) ----------------
__global__ __launch_bounds__(256)
void cvt4(const float* __restrict__ s0, const float* __restrict__ s1,
          const float* __restrict__ s2, const float* __restrict__ s3,
          __bf16* __restrict__ d0, __bf16* __restrict__ d1,
          __bf16* __restrict__ d2, __bf16* __restrict__ d3,
          int n0, int n1, int n2, int n3)
{
    int idx = (blockIdx.x * 256 + threadIdx.x) * 4;
    const float* s; __bf16* d; int off;
    if (idx < n0) { s = s0; d = d0; off = idx; }
    else if (idx < n0 + n1) { s = s1; d = d1; off = idx - n0; }
    else if (idx < n0 + n1 + n2) { s = s2; d = d2; off = idx - n0 - n1; }
    else if (idx < n0 + n1 + n2 + n3) { s = s3; d = d3; off = idx - n0 - n1 - n2; }
    else return;
    f32x4 v = *(const f32x4*)(s + off);
    bf16x4 o;
#pragma unroll
    for (int j = 0; j < 4; ++j) o[j] = (__bf16)v[j];
    *(bf16x4*)(d + off) = o;
}

// ---------------- MFMA GEMM: C(M,N) = A(M,K) @ W(N,K)^T ----------------
// A: f32 (converted in staging), W: bf16 (pre-converted). M,N,K multiples of 64.
__global__ __launch_bounds__(256)
void gemm_bf16(const float* __restrict__ A, const __bf16* __restrict__ W,
               float* __restrict__ C, int M, int N, int K)
{
    __shared__ __bf16 sA[64 * 64];
    __shared__ __bf16 sW[64 * 64];
    const int tid = threadIdx.x;
    const int bm = blockIdx.y * 64, bn = blockIdx.x * 64;
    const int lane = tid & 63, wv = tid >> 6;
    const int m_off = (wv & 1) * 32, n_off = (wv >> 1) * 32;
    const int fr = lane & 15, fq = lane >> 4; // frag row/col, quarter-wave
    f32x4 acc[2][2] = {};

    for (int k0 = 0; k0 < K; k0 += 64) {
#pragma unroll
        for (int i = 0; i < 2; ++i) {
            const int cid = i * 256 + tid;     // 0..511
            const int row = cid >> 3, kc = cid & 7;
            const int slot = kc ^ (row & 7);   // XOR swizzle: conflict-free b128
            const float* sa = A + (size_t)(bm + row) * K + k0 + kc * 8;
            f32x4 v0 = *(const f32x4*)sa;
            f32x4 v1 = *(const f32x4*)(sa + 4);
            bf16x8 ab;
#pragma unroll
            for (int j = 0; j < 4; ++j) { ab[j] = (__bf16)v0[j]; ab[4 + j] = (__bf16)v1[j]; }
            *(bf16x8*)&sA[row * 64 + slot * 8] = ab;
            *(bf16x8*)&sW[row * 64 + slot * 8] =
                *(const bf16x8*)(W + (size_t)(bn + row) * K + k0 + kc * 8);
        }
        __syncthreads();
#pragma unroll
        for (int ks = 0; ks < 2; ++ks) {
            const int kc = ks * 4 + fq;
            const int r0 = m_off + fr, r1 = m_off + 16 + fr;
            const int c0 = n_off + fr, c1 = n_off + 16 + fr;
            bf16x8 a0 = *(const bf16x8*)&sA[r0 * 64 + (kc ^ (r0 & 7)) * 8];
            bf16x8 a1 = *(const bf16x8*)&sA[r1 * 64 + (kc ^ (r1 & 7)) * 8];
            bf16x8 b0 = *(const bf16x8*)&sW[c0 * 64 + (kc ^ (c0 & 7)) * 8];
            bf16x8 b1 = *(const bf16x8*)&sW[c1 * 64 + (kc ^ (c1 & 7)) * 8];
            acc[0][0] = __builtin_amdgcn_mfma_f32_16x16x32_bf16(a0, b0, acc[0][0], 0, 0, 0);
            acc[0][1] = __builtin_amdgcn_mfma_f32_16x16x32_bf16(a0, b1, acc[0][1], 0, 0, 0);
            acc[1][0] = __builtin_amdgcn_mfma_f32_16x16x32_bf16(a1, b0, acc[1][0], 0, 0, 0);
            acc[1][1] = __builtin_amdgcn_mfma_f32_16x16x32_bf16(a1, b1, acc[1][1], 0, 0, 0);
        }
        __syncthreads();
    }
    // C/D layout (m89): col = lane&15, row = (lane>>4)*4 + reg
#pragma unroll
    for (int i = 0; i < 2; ++i)
#pragma unroll
        for (int j = 0; j < 2; ++j)
#pragma unroll
            for (int r = 0; r < 4; ++r)
                C[(size_t)(bm + m_off + i * 16 + fq * 4 + r) * N
                  + bn + n_off + j * 16 + fr] = acc[i][j][r];
}

// ---------------- causal depthwise conv (DC=4) + SiLU ----------------
__global__ __launch_bounds__(256)
void conv_silu(const float* __restrict__ xz, const float* __restrict__ conv_w,
               const float* __restrict__ conv_b, float* __restrict__ xi_out,
               int Bb, int Lb, int DI)
{
    const int idx = blockIdx.x * 256 + threadIdx.x;
    const int total = Bb * Lb * DI;
    if (idx >= total) return;
    const int d = idx % DI;
    const int t = (idx / DI) % Lb;
    const int b = idx / (DI * Lb);
    const float* w = conv_w + (size_t)d * 4;
    float acc = conv_b[d];
    const size_t row2 = (size_t)(b * Lb) * (2 * DI);
#pragma unroll
    for (int j = 0; j < 4; ++j) {
        const int tt = t - 3 + j;
        if (tt >= 0) acc += w[j] * xz[row2 + (size_t)tt * (2 * DI) + d];
    }
    xi_out[idx] = acc / (1.f + __expf(-acc)); // silu
}

// ---------------- fused x_proj + dt_proj(+softplus) ----------------
__global__ __launch_bounds__(256)
void xproj_dt(const float* __restrict__ xi, const float* __restrict__ xproj_w,
              const float* __restrict__ dt_w, const float* __restrict__ dt_b,
              float* __restrict__ x_dbl, float* __restrict__ dt_out,
              int M, int DI, int NX, int R)
{
    __shared__ float s_xi[1024];
    __shared__ float s_dbl[64];
    const int m = blockIdx.x;
    const int tid = threadIdx.x;
    const float* xrow = xi + (size_t)m * DI;
    for (int i = tid; i < DI; i += 256) s_xi[i] = xrow[i];
    __syncthreads();

    const int n = tid >> 2, g = tid & 3;
    if (n < NX) {
        const float* wrow = xproj_w + (size_t)n * DI;
        float acc = 0.f;
        for (int k = g; k < DI; k += 4) acc += s_xi[k] * wrow[k];
        acc += __shfl_xor(acc, 1);
        acc += __shfl_xor(acc, 2);
        if (g == 0) {
            s_dbl[n] = acc;
            x_dbl[(size_t)m * NX + n] = acc;
        }
    }
    __syncthreads();

    const int per = DI / 256;
    for (int ii = 0; ii < per; ++ii) {
        const int d = ii * 256 + tid;
        const float* wr = dt_w + (size_t)d * R;
        float a2 = dt_b[d];
        for (int r2 = 0; r2 < R; ++r2) a2 += s_dbl[r2] * wr[r2];
        dt_out[(size_t)m * DI + d] = fmaxf(a2, 0.f) + log1pf(__expf(-fabsf(a2)));
    }
}

// ---------------- chunked parallel selective scan ----------------
__global__ __launch_bounds__(256)
void scan_p1(const float* __restrict__ dt, const float* __restrict__ xi,
             const float* __restrict__ xdbl, const float* __restrict__ A_log,
             float* __restrict__ wsA, float* __restrict__ wsB,
             int Bb, int Lb, int DI, int NX, int R, int P)
{
    const int tid = threadIdx.x;
    const int s = tid & 15, dl = tid >> 4;
    const int nDB = DI / 16;
    const int cpb = P * nDB;
    const int b = blockIdx.x / cpb;
    const int rem = blockIdx.x % cpb;
    const int c = rem / nDB;
    const int d = (rem % nDB) * 16 + dl;
    const int TC = Lb / P;
    const float A = -__expf(A_log[(size_t)d * 16 + s]);
    float h = 0.f, sdt = 0.f;
    const size_t rowbase = (size_t)b * Lb + (size_t)c * TC;
#pragma unroll 4
    for (int t = 0; t < TC; ++t) {
        const size_t m = rowbase + t;
        const float dtv = dt[m * DI + d];
        const float xv  = xi[m * DI + d];
        const float Bv  = xdbl[m * NX + R + s];
        const float dA = __expf(dtv * A);
        h = fmaf(dA, h, dtv * Bv * xv);
        sdt += dtv;
    }
    const size_t o = ((size_t)(b * P + c) * DI + d) * 16 + s;
    wsA[o] = __expf(sdt * A);  // prod of dA over the chunk
    wsB[o] = h;
}

__global__ __launch_bounds__(256)
void scan_p2(const float* __restrict__ wsA, const float* __restrict__ wsB,
             float* __restrict__ wsH, int Bb, int DI, int P)
{
    const int idx = blockIdx.x * 256 + threadIdx.x;
    const int per_b = DI * 16;
    if (idx >= Bb * per_b) return;
    const int b = idx / per_b, ds_ = idx % per_b;
    float h = 0.f;
    for (int c = 0; c < P; ++c) {
        const size_t o = (size_t)(b * P + c) * per_b + ds_;
        wsH[o] = h;
        h = fmaf(wsA[o], h, wsB[o]);
    }
}

__global__ __launch_bounds__(256)
void scan_p3(const float* __restrict__ dt, const float* __restrict__ xi,
             const float* __restrict__ xdbl, const float* __restrict__ xz,
             const float* __restrict__ A_log, const float* __restrict__ Dp,
             const float* __restrict__ wsH, float* __restrict__ y,
             int Bb, int Lb, int DI, int NX, int R, int P)
{
    const int tid = threadIdx.x;
    const int s = tid & 15, dl = tid >> 4;
    const int nDB = DI / 16;
    const int cpb = P * nDB;
    const int b = blockIdx.x / cpb;
    const int rem = blockIdx.x % cpb;
    const int c = rem / nDB;
    const int d = (rem % nDB) * 16 + dl;
    const int TC = Lb / P;
    const float A = -__expf(A_log[(size_t)d * 16 + s]);
    const float Dv = Dp[d];
    const size_t o = ((size_t)(b * P + c) * DI + d) * 16 + s;
    float h = wsH[o];
    const size_t rowbase = (size_t)b * Lb + (size_t)c * TC;
#pragma unroll 2
    for (int t = 0; t < TC; ++t) {
        const size_t m = rowbase + t;
        const float dtv = dt[m * DI + d];
        const float xv  = xi[m * DI + d];
        const float Bv  = xdbl[m * NX + R + s];
        const float Cv  = xdbl[m * NX + R + 16 + s];
        const float zv  = xz[m * (size_t)(2 * DI) + DI + d];
        const float dA = __expf(dtv * A);
        h = fmaf(dA, h, dtv * Bv * xv);
        float p = h * Cv;
        p += __shfl_xor(p, 1, 16);
        p += __shfl_xor(p, 2, 16);
        p += __shfl_xor(p, 4, 16);
        p += __shfl_xor(p, 8, 16);
        if (s == 0) {
            const float sig = __fdividef(zv, 1.f + __expf(-zv));
            y[m * DI + d] = (p + Dv * xv) * sig;
        }
    }
}

// ---------------- transpose (Bb, R, C) -> (Bb, C, R) ----------------
__global__ void transpose_k(const float* __restrict__ in, float* __restrict__ out,
                            int Bb, int R, int Cc)
{
    __shared__ float tile[32][33];
    const int b = blockIdx.z;
    const int r0 = blockIdx.y * 32, c0 = blockIdx.x * 32;
    const int tx = threadIdx.x, ty = threadIdx.y; // 32x8
    for (int i = ty; i < 32; i += 8) {
        const int r = r0 + i, c = c0 + tx;
        if (r < R && c < Cc) tile[i][tx] = in[((size_t)b * R + r) * Cc + c];
    }
    __syncthreads();
    for (int i = ty; i < 32; i += 8) {
        const int c = c0 + i, r = r0 + tx;
        if (c < Cc && r < R) out[((size_t)b * Cc + c) * R + r] = tile[tx][i];
    }
}

// ---------------- final: out(b,d,l) = x(b,d,l) + hb(b,l,d) ----------------
__global__ __launch_bounds__(256)
void final_add(const float* __restrict__ x, const float* __restrict__ hb,
               float* __restrict__ out)
{
    const int idx = blockIdx.x * 256 + threadIdx.x;
    if (idx >= 2 * 256 * 512) return;
    const int l = idx & 511;
    const int d = (idx >> 9) & 255;
    const int b = idx >> 17;
    out[idx] = x[idx] + hb[(size_t)b * 512 * 256 + (size_t)l * 256 + d];
}

extern "C" void kernel_launch(void* const* d_in, const int* in_sizes, int n_in,
                              void* d_out, int out_size, void* d_ws, size_t ws_size,
                              hipStream_t stream)
{
    const float* x       = (const float*)d_in[0];
    const float* a_in_w  = (const float*)d_in[1];
    const float* a_convw = (const float*)d_in[2];
    const float* a_convb = (const float*)d_in[3];
    const float* a_xproj = (const float*)d_in[4];
    const float* a_dtw   = (const float*)d_in[5];
    const float* a_dtb   = (const float*)d_in[6];
    const float* a_Alog  = (const float*)d_in[7];
    const float* a_Dp    = (const float*)d_in[8];
    const float* a_outw  = (const float*)d_in[9];
    const float* b_in_w  = (const float*)d_in[10];
    const float* b_convw = (const float*)d_in[11];
    const float* b_convb = (const float*)d_in[12];
    const float* b_xproj = (const float*)d_in[13];
    const float* b_dtw   = (const float*)d_in[14];
    const float* b_dtb   = (const float*)d_in[15];
    const float* b_Alog  = (const float*)d_in[16];
    const float* b_Dp    = (const float*)d_in[17];
    const float* b_outw  = (const float*)d_in[18];

    float* ws = (float*)d_ws;
    float* buf_x   = ws;                 // 262144
    float* buf_xz  = buf_x  + 262144;    // 1048576
    float* buf_xi  = buf_xz + 1048576;   // 524288
    float* buf_dbl = buf_xi + 524288;    // 65536
    float* buf_dt  = buf_dbl + 65536;    // 524288
    float* buf_y   = buf_dt + 524288;    // 524288
    float* buf_x2  = buf_y  + 524288;    // 262144
    float* buf_wsA = buf_x2 + 262144;    // 262144
    float* buf_wsB = buf_wsA + 262144;   // 262144
    float* buf_wsH = buf_wsB + 262144;   // 262144
    __bf16* wb      = (__bf16*)(buf_wsH + 262144);
    __bf16* wb_a_in  = wb;                        // 2*2048*512 = 2097152
    __bf16* wb_a_out = wb_a_in + 2097152;         // 2*512*1024 = 1048576
    __bf16* wb_b_in  = wb_a_out + 1048576;        // 2*1024*256 = 524288
    __bf16* wb_b_out = wb_b_in + 524288;          // 2*256*512  = 262144

    // convert all projection weights to bf16 (once per launch)
    {
        const int n0 = 2097152, n1 = 1048576, n2 = 524288, n3 = 262144;
        const int nt = (n0 + n1 + n2 + n3) / 4;
        cvt4<<<(nt + 255) / 256, 256, 0, stream>>>(
            a_in_w, a_outw, b_in_w, b_outw,
            wb_a_in, wb_a_out, wb_b_in, wb_b_out, n0, n1, n2, n3);
    }

    // -------- group a: b=2, l=256, dm=512, di=1024, r=32, NX=64, P=8 --------
    for (int k = 0; k < 2; ++k) {
        const int Bb = 2, Lb = 256, DM = 512, DI = 1024, R = 32, NX = 64, P = 8;
        const int M = Bb * Lb;
        const float* src = (k == 0) ? x : buf_x;
        gemm_bf16<<<dim3(2 * DI / 64, M / 64), 256, 0, stream>>>(
            src, wb_a_in + (size_t)k * 2 * DI * DM, buf_xz, M, 2 * DI, DM);
        conv_silu<<<(M * DI + 255) / 256, 256, 0, stream>>>(
            buf_xz, a_convw + (size_t)k * DI * 4, a_convb + (size_t)k * DI,
            buf_xi, Bb, Lb, DI);
        xproj_dt<<<M, 256, 0, stream>>>(
            buf_xi, a_xproj + (size_t)k * NX * DI, a_dtw + (size_t)k * DI * R,
            a_dtb + (size_t)k * DI, buf_dbl, buf_dt, M, DI, NX, R);
        scan_p1<<<Bb * P * DI / 16, 256, 0, stream>>>(
            buf_dt, buf_xi, buf_dbl, a_Alog + (size_t)k * DI * 16,
            buf_wsA, buf_wsB, Bb, Lb, DI, NX, R, P);
        scan_p2<<<(Bb * DI * 16 + 255) / 256, 256, 0, stream>>>(
            buf_wsA, buf_wsB, buf_wsH, Bb, DI, P);
        scan_p3<<<Bb * P * DI / 16, 256, 0, stream>>>(
            buf_dt, buf_xi, buf_dbl, buf_xz, a_Alog + (size_t)k * DI * 16,
            a_Dp + (size_t)k * DI, buf_wsH, buf_y, Bb, Lb, DI, NX, R, P);
        gemm_bf16<<<dim3(DM / 64, M / 64), 256, 0, stream>>>(
            buf_y, wb_a_out + (size_t)k * DM * DI, buf_x, M, DM, DI);
    }

    // transpose (2,256,512) -> (2,512,256)
    transpose_k<<<dim3(512 / 32, 256 / 32, 2), dim3(32, 8), 0, stream>>>(
        buf_x, buf_x2, 2, 256, 512);

    // -------- group b: b=2, l=512, dm=256, di=512, r=16, NX=48, P=16 --------
    for (int k = 0; k < 2; ++k) {
        const int Bb = 2, Lb = 512, DM = 256, DI = 512, R = 16, NX = 48, P = 16;
        const int M = Bb * Lb;
        const float* src = (k == 0) ? buf_x2 : buf_x;
        gemm_bf16<<<dim3(2 * DI / 64, M / 64), 256, 0, stream>>>(
            src, wb_b_in + (size_t)k * 2 * DI * DM, buf_xz, M, 2 * DI, DM);
        conv_silu<<<(M * DI + 255) / 256, 256, 0, stream>>>(
            buf_xz, b_convw + (size_t)k * DI * 4, b_convb + (size_t)k * DI,
            buf_xi, Bb, Lb, DI);
        xproj_dt<<<M, 256, 0, stream>>>(
            buf_xi, b_xproj + (size_t)k * NX * DI, b_dtw + (size_t)k * DI * R,
            b_dtb + (size_t)k * DI, buf_dbl, buf_dt, M, DI, NX, R);
        scan_p1<<<Bb * P * DI / 16, 256, 0, stream>>>(
            buf_dt, buf_xi, buf_dbl, b_Alog + (size_t)k * DI * 16,
            buf_wsA, buf_wsB, Bb, Lb, DI, NX, R, P);
        scan_p2<<<(Bb * DI * 16 + 255) / 256, 256, 0, stream>>>(
            buf_wsA, buf_wsB, buf_wsH, Bb, DI, P);
        scan_p3<<<Bb * P * DI / 16, 256, 0, stream>>>(
            buf_dt, buf_xi, buf_dbl, buf_xz, b_Alog + (size_t)k * DI * 16,
            b_Dp + (size_t)k * DI, buf_wsH, buf_y, Bb, Lb, DI, NX, R, P);
        gemm_bf16<<<dim3(DM / 64, M / 64), 256, 0, stream>>>(
            buf_y, wb_b_out + (size_t)k * DM * DI, buf_x, M, DM, DI);
    }

    // out = x + transpose(buf_x)
    final_add<<<(2 * 256 * 512 + 255) / 256, 256, 0, stream>>>(
        x, buf_x, (float*)d_out);
}

// Round 5
// 365.533 us; speedup vs baseline: 5.2429x; 1.1214x over previous
//
#include <hip/hip_runtime.h>
#include <cstdint>

typedef float f32x4 __attribute__((ext_vector_type(4)));
typedef __bf16 bf16x8 __attribute__((ext_vector_type(8)));
typedef __bf16 bf16x4 __attribute__((ext_vector_type(4)));

// Problem constants
// B=2, D=256, L=512, NL=2, DS=16, DC=4
// group a: tokens M=512,  dm=512, di=1024, r=32, NX=64->64, P=8
// group b: tokens M=1024, dm=256, di=512,  r=16, NX=48->64, P=16

// ---------------- weight f32 -> bf16 conversion (4 big segments) ----------------
__global__ __launch_bounds__(256)
void cvt4(const float* __restrict__ s0, const float* __restrict__ s1,
          const float* __restrict__ s2, const float* __restrict__ s3,
          __bf16* __restrict__ d0, __bf16* __restrict__ d1,
          __bf16* __restrict__ d2, __bf16* __restrict__ d3,
          int n0, int n1, int n2, int n3)
{
    int idx = (blockIdx.x * 256 + threadIdx.x) * 4;
    const float* s; __bf16* d; int off;
    if (idx < n0) { s = s0; d = d0; off = idx; }
    else if (idx < n0 + n1) { s = s1; d = d1; off = idx - n0; }
    else if (idx < n0 + n1 + n2) { s = s2; d = d2; off = idx - n0 - n1; }
    else if (idx < n0 + n1 + n2 + n3) { s = s3; d = d3; off = idx - n0 - n1 - n2; }
    else return;
    f32x4 v = *(const f32x4*)(s + off);
    bf16x4 o;
#pragma unroll
    for (int j = 0; j < 4; ++j) o[j] = (__bf16)v[j];
    *(bf16x4*)(d + off) = o;
}

// ------- padded conversion: xproj (rows pad to 64) and dt_w (cols pad to 32) -------
__device__ __forceinline__ void cvt_pad_one(const float* src, __bf16* dst, int rem,
                                            int rs, int cs, int rd, int cd)
{
    const int c = rem % cd;
    const int rfull = rem / cd;
    const int layer = rfull / rd;
    const int r = rfull % rd;
    float v = (r < rs && c < cs) ? src[((size_t)layer * rs + r) * cs + c] : 0.f;
    dst[rem] = (__bf16)v;
}

__global__ __launch_bounds__(256)
void cvt_pad4(const float* __restrict__ xp_a, const float* __restrict__ xp_b,
              const float* __restrict__ dt_a, const float* __restrict__ dt_b,
              __bf16* __restrict__ o_xp_a, __bf16* __restrict__ o_xp_b,
              __bf16* __restrict__ o_dt_a, __bf16* __restrict__ o_dt_b)
{
    const int n0 = 131072, n1 = 65536, n2 = 65536, n3 = 32768;
    int idx = blockIdx.x * 256 + threadIdx.x;
    if (idx < n0) cvt_pad_one(xp_a, o_xp_a, idx, 64, 1024, 64, 1024);
    else if (idx < n0 + n1) cvt_pad_one(xp_b, o_xp_b, idx - n0, 48, 512, 64, 512);
    else if (idx < n0 + n1 + n2) cvt_pad_one(dt_a, o_dt_a, idx - n0 - n1, 1024, 32, 1024, 32);
    else if (idx < n0 + n1 + n2 + n3) cvt_pad_one(dt_b, o_dt_b, idx - n0 - n1 - n2, 512, 16, 512, 32);
}

// ---------------- MFMA GEMM: C(M,N) = A(M,K) @ W(N,K)^T ----------------
// A: f32 (converted in staging), W: bf16. M,N,K multiples of 64.
__global__ __launch_bounds__(256)
void gemm_bf16(const float* __restrict__ A, const __bf16* __restrict__ W,
               float* __restrict__ C, int M, int N, int K)
{
    __shared__ __bf16 sA[64 * 64];
    __shared__ __bf16 sW[64 * 64];
    const int tid = threadIdx.x;
    const int bm = blockIdx.y * 64, bn = blockIdx.x * 64;
    const int lane = tid & 63, wv = tid >> 6;
    const int m_off = (wv & 1) * 32, n_off = (wv >> 1) * 32;
    const int fr = lane & 15, fq = lane >> 4;
    f32x4 acc[2][2] = {};

    for (int k0 = 0; k0 < K; k0 += 64) {
#pragma unroll
        for (int i = 0; i < 2; ++i) {
            const int cid = i * 256 + tid;
            const int row = cid >> 3, kc = cid & 7;
            const int slot = kc ^ (row & 7);
            const float* sa = A + (size_t)(bm + row) * K + k0 + kc * 8;
            f32x4 v0 = *(const f32x4*)sa;
            f32x4 v1 = *(const f32x4*)(sa + 4);
            bf16x8 ab;
#pragma unroll
            for (int j = 0; j < 4; ++j) { ab[j] = (__bf16)v0[j]; ab[4 + j] = (__bf16)v1[j]; }
            *(bf16x8*)&sA[row * 64 + slot * 8] = ab;
            *(bf16x8*)&sW[row * 64 + slot * 8] =
                *(const bf16x8*)(W + (size_t)(bn + row) * K + k0 + kc * 8);
        }
        __syncthreads();
#pragma unroll
        for (int ks = 0; ks < 2; ++ks) {
            const int kc = ks * 4 + fq;
            const int r0 = m_off + fr, r1 = m_off + 16 + fr;
            const int c0 = n_off + fr, c1 = n_off + 16 + fr;
            bf16x8 a0 = *(const bf16x8*)&sA[r0 * 64 + (kc ^ (r0 & 7)) * 8];
            bf16x8 a1 = *(const bf16x8*)&sA[r1 * 64 + (kc ^ (r1 & 7)) * 8];
            bf16x8 b0 = *(const bf16x8*)&sW[c0 * 64 + (kc ^ (c0 & 7)) * 8];
            bf16x8 b1 = *(const bf16x8*)&sW[c1 * 64 + (kc ^ (c1 & 7)) * 8];
            acc[0][0] = __builtin_amdgcn_mfma_f32_16x16x32_bf16(a0, b0, acc[0][0], 0, 0, 0);
            acc[0][1] = __builtin_amdgcn_mfma_f32_16x16x32_bf16(a0, b1, acc[0][1], 0, 0, 0);
            acc[1][0] = __builtin_amdgcn_mfma_f32_16x16x32_bf16(a1, b0, acc[1][0], 0, 0, 0);
            acc[1][1] = __builtin_amdgcn_mfma_f32_16x16x32_bf16(a1, b1, acc[1][1], 0, 0, 0);
        }
        __syncthreads();
    }
#pragma unroll
    for (int i = 0; i < 2; ++i)
#pragma unroll
        for (int j = 0; j < 2; ++j)
#pragma unroll
            for (int r = 0; r < 4; ++r)
                C[(size_t)(bm + m_off + i * 16 + fq * 4 + r) * N
                  + bn + n_off + j * 16 + fr] = acc[i][j][r];
}

// ------------- x_proj MFMA GEMM: A bf16, dual f32+bf16 output -------------
__global__ __launch_bounds__(256)
void gemm_xp(const __bf16* __restrict__ A, const __bf16* __restrict__ W,
             float* __restrict__ C, __bf16* __restrict__ Cbf, int M, int N, int K)
{
    __shared__ __bf16 sA[64 * 64];
    __shared__ __bf16 sW[64 * 64];
    const int tid = threadIdx.x;
    const int bm = blockIdx.y * 64, bn = blockIdx.x * 64;
    const int lane = tid & 63, wv = tid >> 6;
    const int m_off = (wv & 1) * 32, n_off = (wv >> 1) * 32;
    const int fr = lane & 15, fq = lane >> 4;
    f32x4 acc[2][2] = {};

    for (int k0 = 0; k0 < K; k0 += 64) {
#pragma unroll
        for (int i = 0; i < 2; ++i) {
            const int cid = i * 256 + tid;
            const int row = cid >> 3, kc = cid & 7;
            const int slot = kc ^ (row & 7);
            *(bf16x8*)&sA[row * 64 + slot * 8] =
                *(const bf16x8*)(A + (size_t)(bm + row) * K + k0 + kc * 8);
            *(bf16x8*)&sW[row * 64 + slot * 8] =
                *(const bf16x8*)(W + (size_t)(bn + row) * K + k0 + kc * 8);
        }
        __syncthreads();
#pragma unroll
        for (int ks = 0; ks < 2; ++ks) {
            const int kc = ks * 4 + fq;
            const int r0 = m_off + fr, r1 = m_off + 16 + fr;
            const int c0 = n_off + fr, c1 = n_off + 16 + fr;
            bf16x8 a0 = *(const bf16x8*)&sA[r0 * 64 + (kc ^ (r0 & 7)) * 8];
            bf16x8 a1 = *(const bf16x8*)&sA[r1 * 64 + (kc ^ (r1 & 7)) * 8];
            bf16x8 b0 = *(const bf16x8*)&sW[c0 * 64 + (kc ^ (c0 & 7)) * 8];
            bf16x8 b1 = *(const bf16x8*)&sW[c1 * 64 + (kc ^ (c1 & 7)) * 8];
            acc[0][0] = __builtin_amdgcn_mfma_f32_16x16x32_bf16(a0, b0, acc[0][0], 0, 0, 0);
            acc[0][1] = __builtin_amdgcn_mfma_f32_16x16x32_bf16(a0, b1, acc[0][1], 0, 0, 0);
            acc[1][0] = __builtin_amdgcn_mfma_f32_16x16x32_bf16(a1, b0, acc[1][0], 0, 0, 0);
            acc[1][1] = __builtin_amdgcn_mfma_f32_16x16x32_bf16(a1, b1, acc[1][1], 0, 0, 0);
        }
        __syncthreads();
    }
#pragma unroll
    for (int i = 0; i < 2; ++i)
#pragma unroll
        for (int j = 0; j < 2; ++j)
#pragma unroll
            for (int r = 0; r < 4; ++r) {
                const size_t o = (size_t)(bm + m_off + i * 16 + fq * 4 + r) * N
                                 + bn + n_off + j * 16 + fr;
                C[o] = acc[i][j][r];
                Cbf[o] = (__bf16)acc[i][j][r];
            }
}

// ------------- dt GEMM (K=32, no LDS) + bias + softplus -------------
// out(M,N) = softplus(A(M,64)[:, :32] @ W(N,32)^T + bias). grid (N/64, M/64).
__global__ __launch_bounds__(256)
void gemm_dt(const __bf16* __restrict__ A, const __bf16* __restrict__ W,
             const float* __restrict__ bias, float* __restrict__ out, int M, int N)
{
    const int tid = threadIdx.x, lane = tid & 63, wv = tid >> 6;
    const int bm = blockIdx.y * 64 + (wv & 1) * 32;
    const int bn = blockIdx.x * 64 + (wv >> 1) * 32;
    const int fr = lane & 15, fq = lane >> 4;
    bf16x8 a0 = *(const bf16x8*)&A[(size_t)(bm + fr) * 64 + fq * 8];
    bf16x8 a1 = *(const bf16x8*)&A[(size_t)(bm + 16 + fr) * 64 + fq * 8];
    bf16x8 b0 = *(const bf16x8*)&W[(size_t)(bn + fr) * 32 + fq * 8];
    bf16x8 b1 = *(const bf16x8*)&W[(size_t)(bn + 16 + fr) * 32 + fq * 8];
    f32x4 acc[2][2] = {};
    acc[0][0] = __builtin_amdgcn_mfma_f32_16x16x32_bf16(a0, b0, acc[0][0], 0, 0, 0);
    acc[0][1] = __builtin_amdgcn_mfma_f32_16x16x32_bf16(a0, b1, acc[0][1], 0, 0, 0);
    acc[1][0] = __builtin_amdgcn_mfma_f32_16x16x32_bf16(a1, b0, acc[1][0], 0, 0, 0);
    acc[1][1] = __builtin_amdgcn_mfma_f32_16x16x32_bf16(a1, b1, acc[1][1], 0, 0, 0);
#pragma unroll
    for (int i = 0; i < 2; ++i)
#pragma unroll
        for (int j = 0; j < 2; ++j) {
            const int col = bn + j * 16 + fr;
            const float bv = bias[col];
#pragma unroll
            for (int r = 0; r < 4; ++r) {
                const float v = acc[i][j][r] + bv;
                out[(size_t)(bm + i * 16 + fq * 4 + r) * N + col] =
                    fmaxf(v, 0.f) + log1pf(__expf(-fabsf(v)));
            }
        }
}

// ---------------- causal depthwise conv (DC=4) + SiLU (f32 + bf16 out) ----------------
__global__ __launch_bounds__(256)
void conv_silu(const float* __restrict__ xz, const float* __restrict__ conv_w,
               const float* __restrict__ conv_b, float* __restrict__ xi_out,
               __bf16* __restrict__ xi_bf, int Bb, int Lb, int DI)
{
    const int idx = blockIdx.x * 256 + threadIdx.x;
    const int total = Bb * Lb * DI;
    if (idx >= total) return;
    const int d = idx % DI;
    const int t = (idx / DI) % Lb;
    const int b = idx / (DI * Lb);
    const float* w = conv_w + (size_t)d * 4;
    float acc = conv_b[d];
    const size_t row2 = (size_t)(b * Lb) * (2 * DI);
#pragma unroll
    for (int j = 0; j < 4; ++j) {
        const int tt = t - 3 + j;
        if (tt >= 0) acc += w[j] * xz[row2 + (size_t)tt * (2 * DI) + d];
    }
    const float v = acc / (1.f + __expf(-acc));
    xi_out[idx] = v;
    xi_bf[idx] = (__bf16)v;
}

// ---------------- chunked parallel selective scan ----------------
// x_dbl stride fixed at 64. B at col R+s, C at col R+16+s.
__global__ __launch_bounds__(256)
void scan_p1(const float* __restrict__ dt, const float* __restrict__ xi,
             const float* __restrict__ xdbl, const float* __restrict__ A_log,
             float* __restrict__ wsA, float* __restrict__ wsB,
             int Bb, int Lb, int DI, int R, int P)
{
    const int tid = threadIdx.x;
    const int s = tid & 15, dl = tid >> 4;
    const int nDB = DI / 16;
    const int cpb = P * nDB;
    const int b = blockIdx.x / cpb;
    const int rem = blockIdx.x % cpb;
    const int c = rem / nDB;
    const int d = (rem % nDB) * 16 + dl;
    const int TC = Lb / P;
    const float A = -__expf(A_log[(size_t)d * 16 + s]);
    float h = 0.f, sdt = 0.f;
    const size_t rowbase = (size_t)b * Lb + (size_t)c * TC;
#pragma unroll 4
    for (int t = 0; t < TC; ++t) {
        const size_t m = rowbase + t;
        const float dtv = dt[m * DI + d];
        const float xv  = xi[m * DI + d];
        const float Bv  = xdbl[m * 64 + R + s];
        const float dA = __expf(dtv * A);
        h = fmaf(dA, h, dtv * Bv * xv);
        sdt += dtv;
    }
    const size_t o = ((size_t)(b * P + c) * DI + d) * 16 + s;
    wsA[o] = __expf(sdt * A);
    wsB[o] = h;
}

__global__ __launch_bounds__(256)
void scan_p2(const float* __restrict__ wsA, const float* __restrict__ wsB,
             float* __restrict__ wsH, int Bb, int DI, int P)
{
    const int idx = blockIdx.x * 256 + threadIdx.x;
    const int per_b = DI * 16;
    if (idx >= Bb * per_b) return;
    const int b = idx / per_b, ds_ = idx % per_b;
    float h = 0.f;
    for (int c = 0; c < P; ++c) {
        const size_t o = (size_t)(b * P + c) * per_b + ds_;
        wsH[o] = h;
        h = fmaf(wsA[o], h, wsB[o]);
    }
}

__global__ __launch_bounds__(256)
void scan_p3(const float* __restrict__ dt, const float* __restrict__ xi,
             const float* __restrict__ xdbl, const float* __restrict__ xz,
             const float* __restrict__ A_log, const float* __restrict__ Dp,
             const float* __restrict__ wsH, float* __restrict__ y,
             int Bb, int Lb, int DI, int R, int P)
{
    const int tid = threadIdx.x;
    const int s = tid & 15, dl = tid >> 4;
    const int nDB = DI / 16;
    const int cpb = P * nDB;
    const int b = blockIdx.x / cpb;
    const int rem = blockIdx.x % cpb;
    const int c = rem / nDB;
    const int d = (rem % nDB) * 16 + dl;
    const int TC = Lb / P;
    const float A = -__expf(A_log[(size_t)d * 16 + s]);
    const float Dv = Dp[d];
    const size_t o = ((size_t)(b * P + c) * DI + d) * 16 + s;
    float h = wsH[o];
    const size_t rowbase = (size_t)b * Lb + (size_t)c * TC;
#pragma unroll 2
    for (int t = 0; t < TC; ++t) {
        const size_t m = rowbase + t;
        const float dtv = dt[m * DI + d];
        const float xv  = xi[m * DI + d];
        const float Bv  = xdbl[m * 64 + R + s];
        const float Cv  = xdbl[m * 64 + R + 16 + s];
        const float zv  = xz[m * (size_t)(2 * DI) + DI + d];
        const float dA = __expf(dtv * A);
        h = fmaf(dA, h, dtv * Bv * xv);
        float p = h * Cv;
        p += __shfl_xor(p, 1, 16);
        p += __shfl_xor(p, 2, 16);
        p += __shfl_xor(p, 4, 16);
        p += __shfl_xor(p, 8, 16);
        if (s == 0) {
            const float sig = __fdividef(zv, 1.f + __expf(-zv));
            y[m * DI + d] = (p + Dv * xv) * sig;
        }
    }
}

// ---------------- transpose (Bb, R, C) -> (Bb, C, R) ----------------
__global__ void transpose_k(const float* __restrict__ in, float* __restrict__ out,
                            int Bb, int R, int Cc)
{
    __shared__ float tile[32][33];
    const int b = blockIdx.z;
    const int r0 = blockIdx.y * 32, c0 = blockIdx.x * 32;
    const int tx = threadIdx.x, ty = threadIdx.y;
    for (int i = ty; i < 32; i += 8) {
        const int r = r0 + i, c = c0 + tx;
        if (r < R && c < Cc) tile[i][tx] = in[((size_t)b * R + r) * Cc + c];
    }
    __syncthreads();
    for (int i = ty; i < 32; i += 8) {
        const int c = c0 + i, r = r0 + tx;
        if (c < Cc && r < R) out[((size_t)b * Cc + c) * R + r] = tile[tx][i];
    }
}

// ---------------- final: out(b,d,l) = x(b,d,l) + hb(b,l,d) ----------------
__global__ __launch_bounds__(256)
void final_add(const float* __restrict__ x, const float* __restrict__ hb,
               float* __restrict__ out)
{
    const int idx = blockIdx.x * 256 + threadIdx.x;
    if (idx >= 2 * 256 * 512) return;
    const int l = idx & 511;
    const int d = (idx >> 9) & 255;
    const int b = idx >> 17;
    out[idx] = x[idx] + hb[(size_t)b * 512 * 256 + (size_t)l * 256 + d];
}

extern "C" void kernel_launch(void* const* d_in, const int* in_sizes, int n_in,
                              void* d_out, int out_size, void* d_ws, size_t ws_size,
                              hipStream_t stream)
{
    const float* x       = (const float*)d_in[0];
    const float* a_in_w  = (const float*)d_in[1];
    const float* a_convw = (const float*)d_in[2];
    const float* a_convb = (const float*)d_in[3];
    const float* a_xproj = (const float*)d_in[4];
    const float* a_dtw   = (const float*)d_in[5];
    const float* a_dtb   = (const float*)d_in[6];
    const float* a_Alog  = (const float*)d_in[7];
    const float* a_Dp    = (const float*)d_in[8];
    const float* a_outw  = (const float*)d_in[9];
    const float* b_in_w  = (const float*)d_in[10];
    const float* b_convw = (const float*)d_in[11];
    const float* b_convb = (const float*)d_in[12];
    const float* b_xproj = (const float*)d_in[13];
    const float* b_dtw   = (const float*)d_in[14];
    const float* b_dtb   = (const float*)d_in[15];
    const float* b_Alog  = (const float*)d_in[16];
    const float* b_Dp    = (const float*)d_in[17];
    const float* b_outw  = (const float*)d_in[18];

    float* ws = (float*)d_ws;
    float* buf_x   = ws;                 // 262144
    float* buf_xz  = buf_x  + 262144;    // 1048576
    float* buf_xi  = buf_xz + 1048576;   // 524288
    float* buf_dbl = buf_xi + 524288;    // 65536 (M x 64, max M=1024)
    float* buf_dt  = buf_dbl + 65536;    // 524288
    float* buf_y   = buf_dt + 524288;    // 524288
    float* buf_x2  = buf_y  + 524288;    // 262144
    float* buf_wsA = buf_x2 + 262144;    // 262144
    float* buf_wsB = buf_wsA + 262144;   // 262144
    float* buf_wsH = buf_wsB + 262144;   // 262144
    __bf16* wb      = (__bf16*)(buf_wsH + 262144);
    __bf16* wb_a_in  = wb;                        // 2097152
    __bf16* wb_a_out = wb_a_in + 2097152;         // 1048576
    __bf16* wb_b_in  = wb_a_out + 1048576;        // 524288
    __bf16* wb_b_out = wb_b_in + 524288;          // 262144
    __bf16* wb_xp_a  = wb_b_out + 262144;         // 131072 (2,64,1024)
    __bf16* wb_xp_b  = wb_xp_a + 131072;          // 65536  (2,64,512) padded
    __bf16* wb_dt_a  = wb_xp_b + 65536;           // 65536  (2,1024,32)
    __bf16* wb_dt_b  = wb_dt_a + 65536;           // 32768  (2,512,32) padded
    __bf16* buf_xi_bf  = wb_dt_b + 32768;         // 524288
    __bf16* buf_dbl_bf = buf_xi_bf + 524288;      // 65536

    // weight conversions (every launch; deterministic)
    {
        const int n0 = 2097152, n1 = 1048576, n2 = 524288, n3 = 262144;
        const int nt = (n0 + n1 + n2 + n3) / 4;
        cvt4<<<(nt + 255) / 256, 256, 0, stream>>>(
            a_in_w, a_outw, b_in_w, b_outw,
            wb_a_in, wb_a_out, wb_b_in, wb_b_out, n0, n1, n2, n3);
        cvt_pad4<<<(131072 + 65536 + 65536 + 32768) / 256, 256, 0, stream>>>(
            a_xproj, b_xproj, a_dtw, b_dtw, wb_xp_a, wb_xp_b, wb_dt_a, wb_dt_b);
    }

    // -------- group a: Bb=2, Lb=256, dm=512, di=1024, R=32, P=8 --------
    for (int k = 0; k < 2; ++k) {
        const int Bb = 2, Lb = 256, DM = 512, DI = 1024, R = 32, P = 8;
        const int M = Bb * Lb;
        const float* src = (k == 0) ? x : buf_x;
        gemm_bf16<<<dim3(2 * DI / 64, M / 64), 256, 0, stream>>>(
            src, wb_a_in + (size_t)k * 2 * DI * DM, buf_xz, M, 2 * DI, DM);
        conv_silu<<<(M * DI + 255) / 256, 256, 0, stream>>>(
            buf_xz, a_convw + (size_t)k * DI * 4, a_convb + (size_t)k * DI,
            buf_xi, buf_xi_bf, Bb, Lb, DI);
        gemm_xp<<<dim3(1, M / 64), 256, 0, stream>>>(
            buf_xi_bf, wb_xp_a + (size_t)k * 64 * DI, buf_dbl, buf_dbl_bf, M, 64, DI);
        gemm_dt<<<dim3(DI / 64, M / 64), 256, 0, stream>>>(
            buf_dbl_bf, wb_dt_a + (size_t)k * DI * 32, a_dtb + (size_t)k * DI,
            buf_dt, M, DI);
        scan_p1<<<Bb * P * DI / 16, 256, 0, stream>>>(
            buf_dt, buf_xi, buf_dbl, a_Alog + (size_t)k * DI * 16,
            buf_wsA, buf_wsB, Bb, Lb, DI, R, P);
        scan_p2<<<(Bb * DI * 16 + 255) / 256, 256, 0, stream>>>(
            buf_wsA, buf_wsB, buf_wsH, Bb, DI, P);
        scan_p3<<<Bb * P * DI / 16, 256, 0, stream>>>(
            buf_dt, buf_xi, buf_dbl, buf_xz, a_Alog + (size_t)k * DI * 16,
            a_Dp + (size_t)k * DI, buf_wsH, buf_y, Bb, Lb, DI, R, P);
        gemm_bf16<<<dim3(DM / 64, M / 64), 256, 0, stream>>>(
            buf_y, wb_a_out + (size_t)k * DM * DI, buf_x, M, DM, DI);
    }

    // transpose (2,256,512) -> (2,512,256)
    transpose_k<<<dim3(512 / 32, 256 / 32, 2), dim3(32, 8), 0, stream>>>(
        buf_x, buf_x2, 2, 256, 512);

    // -------- group b: Bb=2, Lb=512, dm=256, di=512, R=16, P=16 --------
    for (int k = 0; k < 2; ++k) {
        const int Bb = 2, Lb = 512, DM = 256, DI = 512, R = 16, P = 16;
        const int M = Bb * Lb;
        const float* src = (k == 0) ? buf_x2 : buf_x;
        gemm_bf16<<<dim3(2 * DI / 64, M / 64), 256, 0, stream>>>(
            src, wb_b_in + (size_t)k * 2 * DI * DM, buf_xz, M, 2 * DI, DM);
        conv_silu<<<(M * DI + 255) / 256, 256, 0, stream>>>(
            buf_xz, b_convw + (size_t)k * DI * 4, b_convb + (size_t)k * DI,
            buf_xi, buf_xi_bf, Bb, Lb, DI);
        gemm_xp<<<dim3(1, M / 64), 256, 0, stream>>>(
            buf_xi_bf, wb_xp_b + (size_t)k * 64 * DI, buf_dbl, buf_dbl_bf, M, 64, DI);
        gemm_dt<<<dim3(DI / 64, M / 64), 256, 0, stream>>>(
            buf_dbl_bf, wb_dt_b + (size_t)k * DI * 32, b_dtb + (size_t)k * DI,
            buf_dt, M, DI);
        scan_p1<<<Bb * P * DI / 16, 256, 0, stream>>>(
            buf_dt, buf_xi, buf_dbl, b_Alog + (size_t)k * DI * 16,
            buf_wsA, buf_wsB, Bb, Lb, DI, R, P);
        scan_p2<<<(Bb * DI * 16 + 255) / 256, 256, 0, stream>>>(
            buf_wsA, buf_wsB, buf_wsH, Bb, DI, P);
        scan_p3<<<Bb * P * DI / 16, 256, 0, stream>>>(
            buf_dt, buf_xi, buf_dbl, buf_xz, b_Alog + (size_t)k * DI * 16,
            b_Dp + (size_t)k * DI, buf_wsH, buf_y, Bb, Lb, DI, R, P);
        gemm_bf16<<<dim3(DM / 64, M / 64), 256, 0, stream>>>(
            buf_y, wb_b_out + (size_t)k * DM * DI, buf_x, M, DM, DI);
    }

    // out = x + transpose(buf_x)
    final_add<<<(2 * 256 * 512 + 255) / 256, 256, 0, stream>>>(
        x, buf_x, (float*)d_out);
}